// Round 11
// baseline (252.673 us; speedup 1.0000x reference)
//
#include <hip/hip_runtime.h>

// ---------------------------------------------------------------------------
// WindowAttention fused kernel for MI355X (gfx950) — R10 (R4 + micro-opts)
// B=1024 windows, N=64 tokens, C=256, H=8 heads, hd=32
// 512 threads / 8 waves / 1 head per wave; Q,K,P,V register-resident
// (verified transposed-proj + butterfly fragment path).
// LDS = 160 KiB = five 32 KiB bf16 tiles, dead inputs recycled as O tiles.
// R10 changes vs R4 (215us, no-spill baseline):
//  - corner-turn out-proj epilogue: f32x4 stores (32 dwords -> 8 dwordx4)
//  - s_setprio(1/0) around MFMA clusters (phase-role diversity, m191 +4-7%)
//  - sh load moved P2->P3: one tile load per phase P0-P3 (continuous HBM)
// ---------------------------------------------------------------------------

typedef __attribute__((ext_vector_type(8))) __bf16 bf16x8;
typedef __attribute__((ext_vector_type(4))) float f32x4;
typedef __attribute__((ext_vector_type(4))) unsigned short u16x4;

__device__ __forceinline__ unsigned short f2bf(float f) {
  return __builtin_bit_cast(unsigned short, (__bf16)f);
}
__device__ __forceinline__ unsigned pk2(float lo, float hi) {
  return (unsigned)f2bf(lo) | ((unsigned)f2bf(hi) << 16);
}
__device__ __forceinline__ int swz256(int row, int col) {   // 256-elem (512B) rows
  return row * 256 + (col ^ ((row & 31) << 3));
}
__device__ __forceinline__ f32x4 mfma16(bf16x8 a, bf16x8 b, f32x4 c) {
  return __builtin_amdgcn_mfma_f32_16x16x32_bf16(a, b, c, 0, 0, 0);
}

// ---------------- pre-kernel 1: pack weights into fragment layout -----------
// pk[mat][w64][blk][kc][lane][i] = W[64*w64+16*blk+(l&15)][32*kc+8*(l>>4)+i]
__global__ void pack_weights(const float* __restrict__ W0, const float* __restrict__ W1,
                             const float* __restrict__ W2, const float* __restrict__ W3,
                             const float* __restrict__ W4, const float* __restrict__ W5,
                             const float* __restrict__ W6, const float* __restrict__ W7,
                             unsigned short* __restrict__ pk) {
  int t = blockIdx.x * 256 + threadIdx.x;   // 65536 threads
  int mat = t >> 13;
  int w   = (t >> 11) & 3;
  int blk = (t >> 9) & 3;
  int kc  = (t >> 6) & 7;
  int l   = t & 63;
  const float* W = (mat == 0) ? W0 : (mat == 1) ? W1 : (mat == 2) ? W2 : (mat == 3) ? W3
                 : (mat == 4) ? W4 : (mat == 5) ? W5 : (mat == 6) ? W6 : W7;
  const float* src = W + (64 * w + 16 * blk + (l & 15)) * 256 + 32 * kc + 8 * (l >> 4);
  unsigned short* dst = pk + (size_t)t * 8;
#pragma unroll
  for (int i = 0; i < 8; ++i) dst[i] = f2bf(src[i]);
}

// ---------------- pre-kernel 2: bmt[wi][h][qb][t][lane][r] ------------------
// value = mask[wi][q][k] + btab[ridx[q][k]][h], q=16qb+(l&15), k=16t+4(l>>4)+r
__global__ void make_bmt(const float* __restrict__ mask, const float* __restrict__ btab,
                         const int* __restrict__ ridx, float* __restrict__ bmt) {
  int t = blockIdx.x * 256 + threadIdx.x;   // 2,097,152 threads
  int r  = t & 3;
  int l  = (t >> 2) & 63;
  int mf = (t >> 8) & 3;
  int nf = (t >> 10) & 3;
  int h  = (t >> 12) & 7;
  int wi = t >> 15;
  int q = 16 * nf + (l & 15);
  int k = 16 * mf + 4 * (l >> 4) + r;
  bmt[t] = mask[(wi * 64 + q) * 64 + k] + btab[ridx[q * 64 + k] * 8 + h];
}

// ---------------- butterfly: two 16-row C-layout blocks -> one frag ---------
__device__ __forceinline__ bf16x8 butterfly(f32x4 C0, f32x4 C1, int c4, int r16) {
  unsigned a0 = pk2(C0[0], C0[1]), a1 = pk2(C0[2], C0[3]);
  unsigned b0 = pk2(C1[0], C1[1]), b1 = pk2(C1[2], C1[3]);
  int src0 = (((2 * c4) & 3) << 4) + r16;
  int src1 = (((2 * c4 + 1) & 3) << 4) + r16;
  unsigned A0 = (unsigned)__shfl((int)a0, src0);
  unsigned A1 = (unsigned)__shfl((int)a1, src0);
  unsigned A2 = (unsigned)__shfl((int)a0, src1);
  unsigned A3 = (unsigned)__shfl((int)a1, src1);
  unsigned B0 = (unsigned)__shfl((int)b0, src0);
  unsigned B1 = (unsigned)__shfl((int)b1, src0);
  unsigned B2 = (unsigned)__shfl((int)b0, src1);
  unsigned B3 = (unsigned)__shfl((int)b1, src1);
  bool hi = c4 >= 2;
  union { unsigned u[4]; bf16x8 v; } r;
  r.u[0] = hi ? B0 : A0;
  r.u[1] = hi ? B1 : A1;
  r.u[2] = hi ? B2 : A2;
  r.u[3] = hi ? B3 : A3;
  return r.v;
}

// ---------------- staging (512 threads): load->regs, regs->LDS --------------
__device__ __forceinline__ void load_tile(f32x4 r[8], const float* __restrict__ X,
                                          int b, int tid) {
  const f32x4* src = reinterpret_cast<const f32x4*>(X + (size_t)b * 16384);
#pragma unroll
  for (int it = 0; it < 8; ++it) r[it] = src[it * 512 + tid];
}
__device__ __forceinline__ void write_tile(unsigned short* T, const f32x4 r[8], int tid) {
#pragma unroll
  for (int it = 0; it < 8; ++it) {
    int f = it * 512 + tid;
    int row = f >> 6;
    int col = (f & 63) << 2;
    u16x4 p;
    p[0] = f2bf(r[it][0]); p[1] = f2bf(r[it][1]);
    p[2] = f2bf(r[it][2]); p[3] = f2bf(r[it][3]);
    *reinterpret_cast<u16x4*>(T + swz256(row, col)) = p;
  }
}

// per-head packed-weight base: rows [32w, 32w+32) of mat
__device__ __forceinline__ const unsigned short* pwBase(const unsigned short* pk,
                                                        int mat, int w) {
  return pk + mat * 65536 + (w >> 1) * 16384 + (w & 1) * 8192;
}

// ---------------- transposed proj (one head): M = W X^T -> frags ------------
// frag[nf]: lane holds M[d=8c4+i][tok=16nf+r16]  (M incl. bias, *scale)
__device__ __forceinline__ void projT_head(const unsigned short* __restrict__ T,
                                           const unsigned short* __restrict__ pw,
                                           const float* __restrict__ bias, float scale,
                                           int lane, int w, bf16x8 frag[4]) {
  const int r16 = lane & 15, c4 = lane >> 4;
  f32x4 z = {0.f, 0.f, 0.f, 0.f};
  f32x4 acc[2][4];
#pragma unroll
  for (int j = 0; j < 2; ++j)
#pragma unroll
    for (int nf = 0; nf < 4; ++nf) acc[j][nf] = z;
  __builtin_amdgcn_s_setprio(1);
#pragma unroll
  for (int kc = 0; kc < 8; ++kc) {
    bf16x8 aw[2], bx[4];
#pragma unroll
    for (int j = 0; j < 2; ++j)
      aw[j] = *reinterpret_cast<const bf16x8*>(pw + j * 4096 + kc * 512 + lane * 8);
#pragma unroll
    for (int nf = 0; nf < 4; ++nf)
      bx[nf] = *reinterpret_cast<const bf16x8*>(T + swz256(16 * nf + r16, 32 * kc + 8 * c4));
#pragma unroll
    for (int j = 0; j < 2; ++j)
#pragma unroll
      for (int nf = 0; nf < 4; ++nf) acc[j][nf] = mfma16(aw[j], bx[nf], acc[j][nf]);
  }
  __builtin_amdgcn_s_setprio(0);
#pragma unroll
  for (int j = 0; j < 2; ++j) {
    f32x4 b4 = *reinterpret_cast<const f32x4*>(bias + 32 * w + 16 * j + 4 * c4);
#pragma unroll
    for (int nf = 0; nf < 4; ++nf)
#pragma unroll
      for (int r = 0; r < 4; ++r) acc[j][nf][r] = (acc[j][nf][r] + b4[r]) * scale;
  }
#pragma unroll
  for (int nf = 0; nf < 4; ++nf)
    frag[nf] = butterfly(acc[0][nf], acc[1][nf], c4, r16);
}

// ---------------- attention (one head), all-register ------------------------
__device__ __forceinline__ void attn_head(const bf16x8 Qf[4], const bf16x8 Kf[4],
                                          const float* __restrict__ bmb,
                                          int lane, bf16x8 Pf[4][2]) {
  const int r16 = lane & 15, c4 = lane >> 4;
  f32x4 z = {0.f, 0.f, 0.f, 0.f};
#pragma unroll
  for (int qb = 0; qb < 4; ++qb) {
    f32x4 s[4];
    __builtin_amdgcn_s_setprio(1);
#pragma unroll
    for (int t = 0; t < 4; ++t) s[t] = mfma16(Kf[t], Qf[qb], z);
    __builtin_amdgcn_s_setprio(0);
    float mx = -1e30f;
#pragma unroll
    for (int t = 0; t < 4; ++t) {
      f32x4 bm4 = *reinterpret_cast<const f32x4*>(bmb + (((qb * 4 + t) * 64 + lane) << 2));
#pragma unroll
      for (int r = 0; r < 4; ++r) {
        s[t][r] += bm4[r];
        mx = fmaxf(mx, s[t][r]);
      }
    }
    mx = fmaxf(mx, __shfl_xor(mx, 16));
    mx = fmaxf(mx, __shfl_xor(mx, 32));
    float sum = 0.f;
#pragma unroll
    for (int t = 0; t < 4; ++t)
#pragma unroll
      for (int r = 0; r < 4; ++r) {
        s[t][r] = __expf(s[t][r] - mx);
        sum += s[t][r];
      }
    sum += __shfl_xor(sum, 16);
    sum += __shfl_xor(sum, 32);
    float inv = 1.0f / sum;
#pragma unroll
    for (int kc = 0; kc < 2; ++kc) {
      f32x4 p0, p1;
#pragma unroll
      for (int r = 0; r < 4; ++r) {
        p0[r] = s[2 * kc][r] * inv;
        p1[r] = s[2 * kc + 1][r] * inv;
      }
      Pf[qb][kc] = butterfly(p0, p1, c4, r16);
    }
  }
}

// ---------------- normal proj core: acc = T(64x256) @ W^T (32 cols) ---------
__device__ __forceinline__ void projN32(const unsigned short* __restrict__ T,
                                        const unsigned short* __restrict__ pw,
                                        int lane, f32x4 acc[4][2]) {
  const int r16 = lane & 15, c4 = lane >> 4;
  f32x4 z = {0.f, 0.f, 0.f, 0.f};
#pragma unroll
  for (int mf = 0; mf < 4; ++mf)
#pragma unroll
    for (int nf = 0; nf < 2; ++nf) acc[mf][nf] = z;
  __builtin_amdgcn_s_setprio(1);
#pragma unroll
  for (int kc = 0; kc < 8; ++kc) {
    bf16x8 a[4], bb[2];
#pragma unroll
    for (int mf = 0; mf < 4; ++mf)
      a[mf] = *reinterpret_cast<const bf16x8*>(T + swz256(16 * mf + r16, 32 * kc + 8 * c4));
#pragma unroll
    for (int nf = 0; nf < 2; ++nf)
      bb[nf] = *reinterpret_cast<const bf16x8*>(pw + nf * 4096 + kc * 512 + lane * 8);
#pragma unroll
    for (int mf = 0; mf < 4; ++mf)
#pragma unroll
      for (int nf = 0; nf < 2; ++nf) acc[mf][nf] = mfma16(a[mf], bb[nf], acc[mf][nf]);
  }
  __builtin_amdgcn_s_setprio(0);
}

// V epilogue: add per-col bias (d = 32w+16nf+r16), butterfly -> PV B-frags
__device__ __forceinline__ void vFrag(f32x4 acc[4][2], const float* __restrict__ bias,
                                      int lane, int w, bf16x8 Vf[2][2]) {
  const int r16 = lane & 15, c4 = lane >> 4;
#pragma unroll
  for (int nf = 0; nf < 2; ++nf) {
    float bb = bias[32 * w + 16 * nf + r16];
#pragma unroll
    for (int mf = 0; mf < 4; ++mf)
#pragma unroll
      for (int r = 0; r < 4; ++r) acc[mf][nf][r] += bb;
  }
#pragma unroll
  for (int nf = 0; nf < 2; ++nf) {
    Vf[0][nf] = butterfly(acc[0][nf], acc[1][nf], c4, r16);
    Vf[1][nf] = butterfly(acc[2][nf], acc[3][nf], c4, r16);
  }
}

// PV: O = P V for this head -> O tile cols [32w,32w+32)
__device__ __forceinline__ void pv_store(const bf16x8 Pf[4][2], const bf16x8 Vf[2][2],
                                         unsigned short* OS, int lane, int w) {
  const int r16 = lane & 15, c4 = lane >> 4;
  f32x4 z = {0.f, 0.f, 0.f, 0.f};
  f32x4 o[4][2];
#pragma unroll
  for (int qb = 0; qb < 4; ++qb)
#pragma unroll
    for (int nf = 0; nf < 2; ++nf) o[qb][nf] = z;
  __builtin_amdgcn_s_setprio(1);
#pragma unroll
  for (int kc = 0; kc < 2; ++kc)
#pragma unroll
    for (int qb = 0; qb < 4; ++qb)
#pragma unroll
      for (int nf = 0; nf < 2; ++nf)
        o[qb][nf] = mfma16(Pf[qb][kc], Vf[kc][nf], o[qb][nf]);
  __builtin_amdgcn_s_setprio(0);
#pragma unroll
  for (int qb = 0; qb < 4; ++qb)
#pragma unroll
    for (int nf = 0; nf < 2; ++nf)
#pragma unroll
      for (int r = 0; r < 4; ++r)
        OS[swz256(16 * qb + 4 * c4 + r, 32 * w + 16 * nf + r16)] = f2bf(o[qb][nf][r]);
}

// out-proj: projN32 on O tile, add bias, corner-turn, coalesced f32x4 stores
// Corner-turn: source lane(r16,c4) reg r holds M[16mf+4c4+r][32w+16nf+r16];
// target lane(r16,c4) stores f32x4 = M[16mf+r16][32w+16nf+4c4 .. +3].
// elem j comes from lane (4c4+j)+16*(r16>>2), reg (r16&3).
__device__ __forceinline__ void outProj(const unsigned short* __restrict__ OS,
                                        const unsigned short* __restrict__ pw,
                                        const float* __restrict__ bias,
                                        float* __restrict__ dst, int lane, int w) {
  const int r16 = lane & 15, c4 = lane >> 4;
  f32x4 acc[4][2];
  projN32(OS, pw, lane, acc);
  const int rsel = r16 & 3;
  const int sbase = ((r16 >> 2) << 4) + 4 * c4;
#pragma unroll
  for (int mf = 0; mf < 4; ++mf)
#pragma unroll
    for (int nf = 0; nf < 2; ++nf) {
      float bb = bias[32 * w + 16 * nf + r16];
      f32x4 a;
#pragma unroll
      for (int r = 0; r < 4; ++r) a[r] = acc[mf][nf][r] + bb;
      f32x4 v;
#pragma unroll
      for (int j = 0; j < 4; ++j) {
        float t0 = __shfl(a[0], sbase + j);
        float t1 = __shfl(a[1], sbase + j);
        float t2 = __shfl(a[2], sbase + j);
        float t3 = __shfl(a[3], sbase + j);
        v[j] = (rsel == 0) ? t0 : (rsel == 1) ? t1 : (rsel == 2) ? t2 : t3;
      }
      *reinterpret_cast<f32x4*>(dst + (16 * mf + r16) * 256 + 32 * w + 16 * nf + 4 * c4) = v;
    }
}

// ---------------- main fused kernel: one block per window, 8 waves ----------
// LDS: T0..T4 = five 32KB bf16 tiles. Recycling: T0 q->O_x, T1 k->O_s,
// T2 v->O_h, T3 sc, T4 sh. One tile load per phase P0-P3:
//  P0: load q,k -> T0,T1
//  P1: load v;  projT Q(T0), projT K(T1), attn -> Pf; write T2
//  P2: load sc; V(T2)+PV -> T0; write T3
//  P3: load sh; outProj_x(T0); Vs(T3)+PV -> T1; write T4
//  P4: outProj_s(T1); Vh(T4)+PV -> T2
//  P5: outProj_h(T2)
__global__ __launch_bounds__(512, 2) void win_attn(
    const float* __restrict__ gq, const float* __restrict__ gk, const float* __restrict__ gv,
    const float* __restrict__ gsc, const float* __restrict__ gsh,
    const unsigned short* __restrict__ pk,
    const float* __restrict__ b_q, const float* __restrict__ b_k, const float* __restrict__ b_v,
    const float* __restrict__ b_vs, const float* __restrict__ b_vh,
    const float* __restrict__ b_px, const float* __restrict__ b_ps, const float* __restrict__ b_ph,
    const float* __restrict__ bmt, float* __restrict__ out) {
  __shared__ __align__(16) unsigned short sm[81920];   // 160 KiB
  unsigned short* T0 = sm;                // q   -> O_x
  unsigned short* T1 = sm + 16384;        // k   -> O_s
  unsigned short* T2 = sm + 32768;        // v   -> O_h
  unsigned short* T3 = sm + 49152;        // sc
  unsigned short* T4 = sm + 65536;        // sh

  const int b    = blockIdx.x;
  const int tid  = threadIdx.x;
  const int lane = tid & 63;
  const int w    = tid >> 6;          // wave id == head id
  const int wi   = b & 63;

  bf16x8 Qf[4], Kf[4], Pf[4][2], Vf[2][2];

  // P0: load q,k; write T0,T1
  {
    f32x4 rA[8], rB[8];
    load_tile(rA, gq, b, tid);
    load_tile(rB, gk, b, tid);
    write_tile(T0, rA, tid);
    write_tile(T1, rB, tid);
  }
  __syncthreads();                                    // bar0

  // P1: load v; Q,K projections + attention (register-only result Pf); write T2
  {
    f32x4 rA[8];
    load_tile(rA, gv, b, tid);
    projT_head(T0, pwBase(pk, 0, w), b_q, 0.17677669529663687f, lane, w, Qf);
    projT_head(T1, pwBase(pk, 1, w), b_k, 1.0f, lane, w, Kf);
    attn_head(Qf, Kf, bmt + ((size_t)(wi * 8 + w) << 12), lane, Pf);
    write_tile(T2, rA, tid);
  }
  __syncthreads();                                    // bar1

  // P2: load sc; V proj + PV -> O_x into T0; write T3
  {
    f32x4 rA[8];
    load_tile(rA, gsc, b, tid);
    {
      f32x4 acc[4][2];
      projN32(T2, pwBase(pk, 2, w), lane, acc);
      vFrag(acc, b_v, lane, w, Vf);
    }
    pv_store(Pf, Vf, T0, lane, w);
    write_tile(T3, rA, tid);
  }
  __syncthreads();                                    // bar2

  // P3: load sh; out-proj x (T0); Vs proj (T3) + PV -> O_s into T1; write T4
  {
    f32x4 rA[8];
    load_tile(rA, gsh, b, tid);
    outProj(T0, pwBase(pk, 5, w), b_px, out + (size_t)b * 16384, lane, w);
    {
      f32x4 acc[4][2];
      projN32(T3, pwBase(pk, 3, w), lane, acc);
      vFrag(acc, b_vs, lane, w, Vf);
    }
    pv_store(Pf, Vf, T1, lane, w);
    write_tile(T4, rA, tid);
  }
  __syncthreads();                                    // bar3

  // P4: out-proj s (T1); Vh proj (T4) + PV -> O_h into T2
  outProj(T1, pwBase(pk, 6, w), b_ps, out + 16777216 + (size_t)b * 16384, lane, w);
  {
    f32x4 acc[4][2];
    projN32(T4, pwBase(pk, 4, w), lane, acc);
    vFrag(acc, b_vh, lane, w, Vf);
  }
  pv_store(Pf, Vf, T2, lane, w);
  __syncthreads();                                    // bar4

  // P5: out-proj h (T2)
  outProj(T2, pwBase(pk, 7, w), b_ph, out + 33554432 + (size_t)b * 16384, lane, w);
}

// ---------------------------------------------------------------------------
extern "C" void kernel_launch(void* const* d_in, const int* in_sizes, int n_in,
                              void* d_out, int out_size, void* d_ws, size_t ws_size,
                              hipStream_t stream) {
  const float* Xq   = (const float*)d_in[0];
  const float* Xk   = (const float*)d_in[1];
  const float* Xv   = (const float*)d_in[2];
  const float* Xsc  = (const float*)d_in[3];
  const float* Xsh  = (const float*)d_in[4];
  const float* mask = (const float*)d_in[5];
  const float* Wq   = (const float*)d_in[6];  const float* bq  = (const float*)d_in[7];
  const float* Wk   = (const float*)d_in[8];  const float* bk  = (const float*)d_in[9];
  const float* Wv   = (const float*)d_in[10]; const float* bv  = (const float*)d_in[11];
  const float* Wvs  = (const float*)d_in[12]; const float* bvs = (const float*)d_in[13];
  const float* Wvh  = (const float*)d_in[14]; const float* bvh = (const float*)d_in[15];
  const float* Wpx  = (const float*)d_in[16]; const float* bpx = (const float*)d_in[17];
  const float* Wps  = (const float*)d_in[18]; const float* bps = (const float*)d_in[19];
  const float* Wph  = (const float*)d_in[20]; const float* bph = (const float*)d_in[21];
  const float* btab = (const float*)d_in[22];
  const int*   ridx = (const int*)d_in[23];

  unsigned short* pk = (unsigned short*)d_ws;                  // 8 mats x 128KB = 1 MB
  float* bmt = (float*)((char*)d_ws + (size_t)8 * 65536 * 2);  // 2M floats = 8 MB

  pack_weights<<<256, 256, 0, stream>>>(Wq, Wk, Wv, Wvs, Wvh, Wpx, Wps, Wph, pk);
  make_bmt<<<8192, 256, 0, stream>>>(mask, btab, ridx, bmt);
  win_attn<<<1024, 512, 0, stream>>>(Xq, Xk, Xv, Xsc, Xsh, pk,
                                     bq, bk, bv, bvs, bvh, bpx, bps, bph,
                                     bmt, (float*)d_out);
}

// Round 12
// 216.519 us; speedup vs baseline: 1.1670x; 1.1670x over previous
//
#include <hip/hip_runtime.h>

// ---------------------------------------------------------------------------
// WindowAttention fused kernel for MI355X (gfx950) — R11 (= R4 exact + setprio)
// B=1024 windows, N=64 tokens, C=256, H=8 heads, hd=32
// 512 threads / 8 waves / 1 head per wave. Q,K,P,V register-resident
// (verified transposed-proj + butterfly fragment path).
// LDS = 160 KiB = five 32 KiB bf16 input tiles; dead input tiles recycled as
// O tiles. 6 phases / 5 barriers (the 215us no-spill baseline schedule).
// R11 change vs R4: s_setprio(1/0) wrapped around MFMA clusters ONLY
// (R10's corner-turn + phase re-pack reverted: bank conflicts 3.7M->10M).
// ---------------------------------------------------------------------------

typedef __attribute__((ext_vector_type(8))) __bf16 bf16x8;
typedef __attribute__((ext_vector_type(4))) float f32x4;
typedef __attribute__((ext_vector_type(4))) unsigned short u16x4;

__device__ __forceinline__ unsigned short f2bf(float f) {
  return __builtin_bit_cast(unsigned short, (__bf16)f);
}
__device__ __forceinline__ unsigned pk2(float lo, float hi) {
  return (unsigned)f2bf(lo) | ((unsigned)f2bf(hi) << 16);
}
__device__ __forceinline__ int swz256(int row, int col) {   // 256-elem (512B) rows
  return row * 256 + (col ^ ((row & 31) << 3));
}
__device__ __forceinline__ f32x4 mfma16(bf16x8 a, bf16x8 b, f32x4 c) {
  return __builtin_amdgcn_mfma_f32_16x16x32_bf16(a, b, c, 0, 0, 0);
}

// ---------------- pre-kernel 1: pack weights into fragment layout -----------
// pk[mat][w64][blk][kc][lane][i] = W[64*w64+16*blk+(l&15)][32*kc+8*(l>>4)+i]
__global__ void pack_weights(const float* __restrict__ W0, const float* __restrict__ W1,
                             const float* __restrict__ W2, const float* __restrict__ W3,
                             const float* __restrict__ W4, const float* __restrict__ W5,
                             const float* __restrict__ W6, const float* __restrict__ W7,
                             unsigned short* __restrict__ pk) {
  int t = blockIdx.x * 256 + threadIdx.x;   // 65536 threads
  int mat = t >> 13;
  int w   = (t >> 11) & 3;
  int blk = (t >> 9) & 3;
  int kc  = (t >> 6) & 7;
  int l   = t & 63;
  const float* W = (mat == 0) ? W0 : (mat == 1) ? W1 : (mat == 2) ? W2 : (mat == 3) ? W3
                 : (mat == 4) ? W4 : (mat == 5) ? W5 : (mat == 6) ? W6 : W7;
  const float* src = W + (64 * w + 16 * blk + (l & 15)) * 256 + 32 * kc + 8 * (l >> 4);
  unsigned short* dst = pk + (size_t)t * 8;
#pragma unroll
  for (int i = 0; i < 8; ++i) dst[i] = f2bf(src[i]);
}

// ---------------- pre-kernel 2: bmt[wi][h][qb][t][lane][r] ------------------
// value = mask[wi][q][k] + btab[ridx[q][k]][h], q=16qb+(l&15), k=16t+4(l>>4)+r
__global__ void make_bmt(const float* __restrict__ mask, const float* __restrict__ btab,
                         const int* __restrict__ ridx, float* __restrict__ bmt) {
  int t = blockIdx.x * 256 + threadIdx.x;   // 2,097,152 threads
  int r  = t & 3;
  int l  = (t >> 2) & 63;
  int mf = (t >> 8) & 3;
  int nf = (t >> 10) & 3;
  int h  = (t >> 12) & 7;
  int wi = t >> 15;
  int q = 16 * nf + (l & 15);
  int k = 16 * mf + 4 * (l >> 4) + r;
  bmt[t] = mask[(wi * 64 + q) * 64 + k] + btab[ridx[q * 64 + k] * 8 + h];
}

// ---------------- butterfly: two 16-row C-layout blocks -> one frag ---------
__device__ __forceinline__ bf16x8 butterfly(f32x4 C0, f32x4 C1, int c4, int r16) {
  unsigned a0 = pk2(C0[0], C0[1]), a1 = pk2(C0[2], C0[3]);
  unsigned b0 = pk2(C1[0], C1[1]), b1 = pk2(C1[2], C1[3]);
  int src0 = (((2 * c4) & 3) << 4) + r16;
  int src1 = (((2 * c4 + 1) & 3) << 4) + r16;
  unsigned A0 = (unsigned)__shfl((int)a0, src0);
  unsigned A1 = (unsigned)__shfl((int)a1, src0);
  unsigned A2 = (unsigned)__shfl((int)a0, src1);
  unsigned A3 = (unsigned)__shfl((int)a1, src1);
  unsigned B0 = (unsigned)__shfl((int)b0, src0);
  unsigned B1 = (unsigned)__shfl((int)b1, src0);
  unsigned B2 = (unsigned)__shfl((int)b0, src1);
  unsigned B3 = (unsigned)__shfl((int)b1, src1);
  bool hi = c4 >= 2;
  union { unsigned u[4]; bf16x8 v; } r;
  r.u[0] = hi ? B0 : A0;
  r.u[1] = hi ? B1 : A1;
  r.u[2] = hi ? B2 : A2;
  r.u[3] = hi ? B3 : A3;
  return r.v;
}

// ---------------- staging (512 threads): load->regs, regs->LDS --------------
__device__ __forceinline__ void load_tile(f32x4 r[8], const float* __restrict__ X,
                                          int b, int tid) {
  const f32x4* src = reinterpret_cast<const f32x4*>(X + (size_t)b * 16384);
#pragma unroll
  for (int it = 0; it < 8; ++it) r[it] = src[it * 512 + tid];
}
__device__ __forceinline__ void write_tile(unsigned short* T, const f32x4 r[8], int tid) {
#pragma unroll
  for (int it = 0; it < 8; ++it) {
    int f = it * 512 + tid;
    int row = f >> 6;
    int col = (f & 63) << 2;
    u16x4 p;
    p[0] = f2bf(r[it][0]); p[1] = f2bf(r[it][1]);
    p[2] = f2bf(r[it][2]); p[3] = f2bf(r[it][3]);
    *reinterpret_cast<u16x4*>(T + swz256(row, col)) = p;
  }
}

// per-head packed-weight base: rows [32w, 32w+32) of mat
__device__ __forceinline__ const unsigned short* pwBase(const unsigned short* pk,
                                                        int mat, int w) {
  return pk + mat * 65536 + (w >> 1) * 16384 + (w & 1) * 8192;
}

// ---------------- transposed proj (one head): M = W X^T -> frags ------------
// frag[nf]: lane holds M[d=8c4+i][tok=16nf+r16]  (M incl. bias, *scale)
__device__ __forceinline__ void projT_head(const unsigned short* __restrict__ T,
                                           const unsigned short* __restrict__ pw,
                                           const float* __restrict__ bias, float scale,
                                           int lane, int w, bf16x8 frag[4]) {
  const int r16 = lane & 15, c4 = lane >> 4;
  f32x4 z = {0.f, 0.f, 0.f, 0.f};
  f32x4 acc[2][4];
#pragma unroll
  for (int j = 0; j < 2; ++j)
#pragma unroll
    for (int nf = 0; nf < 4; ++nf) acc[j][nf] = z;
  __builtin_amdgcn_s_setprio(1);
#pragma unroll
  for (int kc = 0; kc < 8; ++kc) {
    bf16x8 aw[2], bx[4];
#pragma unroll
    for (int j = 0; j < 2; ++j)
      aw[j] = *reinterpret_cast<const bf16x8*>(pw + j * 4096 + kc * 512 + lane * 8);
#pragma unroll
    for (int nf = 0; nf < 4; ++nf)
      bx[nf] = *reinterpret_cast<const bf16x8*>(T + swz256(16 * nf + r16, 32 * kc + 8 * c4));
#pragma unroll
    for (int j = 0; j < 2; ++j)
#pragma unroll
      for (int nf = 0; nf < 4; ++nf) acc[j][nf] = mfma16(aw[j], bx[nf], acc[j][nf]);
  }
  __builtin_amdgcn_s_setprio(0);
#pragma unroll
  for (int j = 0; j < 2; ++j) {
    f32x4 b4 = *reinterpret_cast<const f32x4*>(bias + 32 * w + 16 * j + 4 * c4);
#pragma unroll
    for (int nf = 0; nf < 4; ++nf)
#pragma unroll
      for (int r = 0; r < 4; ++r) acc[j][nf][r] = (acc[j][nf][r] + b4[r]) * scale;
  }
#pragma unroll
  for (int nf = 0; nf < 4; ++nf)
    frag[nf] = butterfly(acc[0][nf], acc[1][nf], c4, r16);
}

// ---------------- attention (one head), all-register ------------------------
__device__ __forceinline__ void attn_head(const bf16x8 Qf[4], const bf16x8 Kf[4],
                                          const float* __restrict__ bmb,
                                          int lane, bf16x8 Pf[4][2]) {
  const int r16 = lane & 15, c4 = lane >> 4;
  f32x4 z = {0.f, 0.f, 0.f, 0.f};
#pragma unroll
  for (int qb = 0; qb < 4; ++qb) {
    f32x4 s[4];
    __builtin_amdgcn_s_setprio(1);
#pragma unroll
    for (int t = 0; t < 4; ++t) s[t] = mfma16(Kf[t], Qf[qb], z);
    __builtin_amdgcn_s_setprio(0);
    float mx = -1e30f;
#pragma unroll
    for (int t = 0; t < 4; ++t) {
      f32x4 bm4 = *reinterpret_cast<const f32x4*>(bmb + (((qb * 4 + t) * 64 + lane) << 2));
#pragma unroll
      for (int r = 0; r < 4; ++r) {
        s[t][r] += bm4[r];
        mx = fmaxf(mx, s[t][r]);
      }
    }
    mx = fmaxf(mx, __shfl_xor(mx, 16));
    mx = fmaxf(mx, __shfl_xor(mx, 32));
    float sum = 0.f;
#pragma unroll
    for (int t = 0; t < 4; ++t)
#pragma unroll
      for (int r = 0; r < 4; ++r) {
        s[t][r] = __expf(s[t][r] - mx);
        sum += s[t][r];
      }
    sum += __shfl_xor(sum, 16);
    sum += __shfl_xor(sum, 32);
    float inv = 1.0f / sum;
#pragma unroll
    for (int kc = 0; kc < 2; ++kc) {
      f32x4 p0, p1;
#pragma unroll
      for (int r = 0; r < 4; ++r) {
        p0[r] = s[2 * kc][r] * inv;
        p1[r] = s[2 * kc + 1][r] * inv;
      }
      Pf[qb][kc] = butterfly(p0, p1, c4, r16);
    }
  }
}

// ---------------- normal proj core: acc = T(64x256) @ W^T (32 cols) ---------
__device__ __forceinline__ void projN32(const unsigned short* __restrict__ T,
                                        const unsigned short* __restrict__ pw,
                                        int lane, f32x4 acc[4][2]) {
  const int r16 = lane & 15, c4 = lane >> 4;
  f32x4 z = {0.f, 0.f, 0.f, 0.f};
#pragma unroll
  for (int mf = 0; mf < 4; ++mf)
#pragma unroll
    for (int nf = 0; nf < 2; ++nf) acc[mf][nf] = z;
  __builtin_amdgcn_s_setprio(1);
#pragma unroll
  for (int kc = 0; kc < 8; ++kc) {
    bf16x8 a[4], bb[2];
#pragma unroll
    for (int mf = 0; mf < 4; ++mf)
      a[mf] = *reinterpret_cast<const bf16x8*>(T + swz256(16 * mf + r16, 32 * kc + 8 * c4));
#pragma unroll
    for (int nf = 0; nf < 2; ++nf)
      bb[nf] = *reinterpret_cast<const bf16x8*>(pw + nf * 4096 + kc * 512 + lane * 8);
#pragma unroll
    for (int mf = 0; mf < 4; ++mf)
#pragma unroll
      for (int nf = 0; nf < 2; ++nf) acc[mf][nf] = mfma16(a[mf], bb[nf], acc[mf][nf]);
  }
  __builtin_amdgcn_s_setprio(0);
}

// V epilogue: add per-col bias (d = 32w+16nf+r16), butterfly -> PV B-frags
__device__ __forceinline__ void vFrag(f32x4 acc[4][2], const float* __restrict__ bias,
                                      int lane, int w, bf16x8 Vf[2][2]) {
  const int r16 = lane & 15, c4 = lane >> 4;
#pragma unroll
  for (int nf = 0; nf < 2; ++nf) {
    float bb = bias[32 * w + 16 * nf + r16];
#pragma unroll
    for (int mf = 0; mf < 4; ++mf)
#pragma unroll
      for (int r = 0; r < 4; ++r) acc[mf][nf][r] += bb;
  }
#pragma unroll
  for (int nf = 0; nf < 2; ++nf) {
    Vf[0][nf] = butterfly(acc[0][nf], acc[1][nf], c4, r16);
    Vf[1][nf] = butterfly(acc[2][nf], acc[3][nf], c4, r16);
  }
}

// PV: O = P V for this head -> O tile cols [32w,32w+32)
__device__ __forceinline__ void pv_store(const bf16x8 Pf[4][2], const bf16x8 Vf[2][2],
                                         unsigned short* OS, int lane, int w) {
  const int r16 = lane & 15, c4 = lane >> 4;
  f32x4 z = {0.f, 0.f, 0.f, 0.f};
  f32x4 o[4][2];
#pragma unroll
  for (int qb = 0; qb < 4; ++qb)
#pragma unroll
    for (int nf = 0; nf < 2; ++nf) o[qb][nf] = z;
  __builtin_amdgcn_s_setprio(1);
#pragma unroll
  for (int kc = 0; kc < 2; ++kc)
#pragma unroll
    for (int qb = 0; qb < 4; ++qb)
#pragma unroll
      for (int nf = 0; nf < 2; ++nf)
        o[qb][nf] = mfma16(Pf[qb][kc], Vf[kc][nf], o[qb][nf]);
  __builtin_amdgcn_s_setprio(0);
#pragma unroll
  for (int qb = 0; qb < 4; ++qb)
#pragma unroll
    for (int nf = 0; nf < 2; ++nf)
#pragma unroll
      for (int r = 0; r < 4; ++r)
        OS[swz256(16 * qb + 4 * c4 + r, 32 * w + 16 * nf + r16)] = f2bf(o[qb][nf][r]);
}

// out-proj: projN32 on O tile, add bias, store fp32 global (64B segments)
__device__ __forceinline__ void outProj(const unsigned short* __restrict__ OS,
                                        const unsigned short* __restrict__ pw,
                                        const float* __restrict__ bias,
                                        float* __restrict__ dst, int lane, int w) {
  const int r16 = lane & 15, c4 = lane >> 4;
  f32x4 acc[4][2];
  projN32(OS, pw, lane, acc);
#pragma unroll
  for (int nf = 0; nf < 2; ++nf) {
    float bb = bias[32 * w + 16 * nf + r16];
#pragma unroll
    for (int mf = 0; mf < 4; ++mf)
#pragma unroll
      for (int r = 0; r < 4; ++r)
        dst[(16 * mf + 4 * c4 + r) * 256 + 32 * w + 16 * nf + r16] = acc[mf][nf][r] + bb;
  }
}

// ---------------- main fused kernel: one block per window, 8 waves ----------
// LDS: T0..T4 = five 32KB bf16 tiles (q,k,v,sc,sh). Recycling:
//   P2: O_x -> T0 (q dead)   P3: O_s -> T1 (k dead)   P4: O_h -> T2 (v dead)
__global__ __launch_bounds__(512, 2) void win_attn(
    const float* __restrict__ gq, const float* __restrict__ gk, const float* __restrict__ gv,
    const float* __restrict__ gsc, const float* __restrict__ gsh,
    const unsigned short* __restrict__ pk,
    const float* __restrict__ b_q, const float* __restrict__ b_k, const float* __restrict__ b_v,
    const float* __restrict__ b_vs, const float* __restrict__ b_vh,
    const float* __restrict__ b_px, const float* __restrict__ b_ps, const float* __restrict__ b_ph,
    const float* __restrict__ bmt, float* __restrict__ out) {
  __shared__ __align__(16) unsigned short sm[81920];   // 160 KiB
  unsigned short* T0 = sm;                // q   -> O_x
  unsigned short* T1 = sm + 16384;        // k   -> O_s
  unsigned short* T2 = sm + 32768;        // v   -> O_h
  unsigned short* T3 = sm + 49152;        // sc
  unsigned short* T4 = sm + 65536;        // sh

  const int b    = blockIdx.x;
  const int tid  = threadIdx.x;
  const int lane = tid & 63;
  const int w    = tid >> 6;          // wave id == head id
  const int wi   = b & 63;

  bf16x8 Qf[4], Kf[4], Pf[4][2], Vf[2][2];

  // P0: load q,k; write T0,T1
  {
    f32x4 rA[8], rB[8];
    load_tile(rA, gq, b, tid);
    load_tile(rB, gk, b, tid);
    write_tile(T0, rA, tid);
    write_tile(T1, rB, tid);
  }
  __syncthreads();                                    // bar0

  // P1: load v; Q,K projections + attention (register-only result Pf); write T2
  {
    f32x4 rA[8];
    load_tile(rA, gv, b, tid);
    projT_head(T0, pwBase(pk, 0, w), b_q, 0.17677669529663687f, lane, w, Qf);
    projT_head(T1, pwBase(pk, 1, w), b_k, 1.0f, lane, w, Kf);
    attn_head(Qf, Kf, bmt + ((size_t)(wi * 8 + w) << 12), lane, Pf);
    write_tile(T2, rA, tid);
  }
  __syncthreads();                                    // bar1

  // P2: load sc,sh; V proj + PV -> O_x into T0; write T3,T4
  {
    f32x4 rA[8], rB[8];
    load_tile(rA, gsc, b, tid);
    load_tile(rB, gsh, b, tid);
    {
      f32x4 acc[4][2];
      projN32(T2, pwBase(pk, 2, w), lane, acc);
      vFrag(acc, b_v, lane, w, Vf);
    }
    pv_store(Pf, Vf, T0, lane, w);
    write_tile(T3, rA, tid);
    write_tile(T4, rB, tid);
  }
  __syncthreads();                                    // bar2

  // P3: out-proj x (T0); Vs proj (T3) + PV -> O_s into T1
  outProj(T0, pwBase(pk, 5, w), b_px, out + (size_t)b * 16384, lane, w);
  {
    f32x4 acc[4][2];
    projN32(T3, pwBase(pk, 3, w), lane, acc);
    vFrag(acc, b_vs, lane, w, Vf);
  }
  pv_store(Pf, Vf, T1, lane, w);
  __syncthreads();                                    // bar3

  // P4: out-proj s (T1); Vh proj (T4) + PV -> O_h into T2
  outProj(T1, pwBase(pk, 6, w), b_ps, out + 16777216 + (size_t)b * 16384, lane, w);
  {
    f32x4 acc[4][2];
    projN32(T4, pwBase(pk, 4, w), lane, acc);
    vFrag(acc, b_vh, lane, w, Vf);
  }
  pv_store(Pf, Vf, T2, lane, w);
  __syncthreads();                                    // bar4

  // P5: out-proj h (T2)
  outProj(T2, pwBase(pk, 7, w), b_ph, out + 33554432 + (size_t)b * 16384, lane, w);
}

// ---------------------------------------------------------------------------
extern "C" void kernel_launch(void* const* d_in, const int* in_sizes, int n_in,
                              void* d_out, int out_size, void* d_ws, size_t ws_size,
                              hipStream_t stream) {
  const float* Xq   = (const float*)d_in[0];
  const float* Xk   = (const float*)d_in[1];
  const float* Xv   = (const float*)d_in[2];
  const float* Xsc  = (const float*)d_in[3];
  const float* Xsh  = (const float*)d_in[4];
  const float* mask = (const float*)d_in[5];
  const float* Wq   = (const float*)d_in[6];  const float* bq  = (const float*)d_in[7];
  const float* Wk   = (const float*)d_in[8];  const float* bk  = (const float*)d_in[9];
  const float* Wv   = (const float*)d_in[10]; const float* bv  = (const float*)d_in[11];
  const float* Wvs  = (const float*)d_in[12]; const float* bvs = (const float*)d_in[13];
  const float* Wvh  = (const float*)d_in[14]; const float* bvh = (const float*)d_in[15];
  const float* Wpx  = (const float*)d_in[16]; const float* bpx = (const float*)d_in[17];
  const float* Wps  = (const float*)d_in[18]; const float* bps = (const float*)d_in[19];
  const float* Wph  = (const float*)d_in[20]; const float* bph = (const float*)d_in[21];
  const float* btab = (const float*)d_in[22];
  const int*   ridx = (const int*)d_in[23];

  unsigned short* pk = (unsigned short*)d_ws;                  // 8 mats x 128KB = 1 MB
  float* bmt = (float*)((char*)d_ws + (size_t)8 * 65536 * 2);  // 2M floats = 8 MB

  pack_weights<<<256, 256, 0, stream>>>(Wq, Wk, Wv, Wvs, Wvh, Wpx, Wps, Wph, pk);
  make_bmt<<<8192, 256, 0, stream>>>(mask, btab, ridx, bmt);
  win_attn<<<1024, 512, 0, stream>>>(Xq, Xk, Xv, Xsc, Xsh, pk,
                                     bq, bk, bv, bvs, bvh, bpx, bps, bph,
                                     bmt, (float*)d_out);
}